// Round 2
// baseline (267.541 us; speedup 1.0000x reference)
//
#include <hip/hip_runtime.h>

#define D_MODEL 1024
#define D_STATE 16
#define DT_RANK 64
#define BATCH 2
#define SEQLEN 4096
#define CHUNK 64
#define NCHUNK (SEQLEN / CHUNK)          // 64
#define NROWS (BATCH * SEQLEN)           // 8192
#define E_DIM (DT_RANK + 2 * D_STATE)    // 96

// ---------------------------------------------------------------------------
// Kernel 1: dtBC[m][e] = sum_k x[m][k] * Wx[e][k]   (M=8192, N=96, K=1024)
// Tiled fp32 GEMM: BM=32 rows, BN=96 (all cols), BK=64. 128 threads/block.
// Micro-tile per thread: 4 rows x 6 cols. LDS staged transposed, padded.
// ---------------------------------------------------------------------------
#define G1_BM 32
#define G1_BK 64

__global__ __launch_bounds__(128)
void k_gemm1(const float* __restrict__ x, const float* __restrict__ W,
             float* __restrict__ dtBC) {
  __shared__ float sX[G1_BK][G1_BM + 4];   // [k][r], stride 36
  __shared__ float sW[G1_BK][E_DIM + 1];   // [k][e], stride 97
  const int tid = threadIdx.x;
  const int m0 = blockIdx.x * G1_BM;
  const int tx = tid & 7;          // row group: rows tx*4 .. tx*4+3
  const int ty = tid >> 3;         // col group: cols ty*6 .. ty*6+5

  float acc[4][6];
  #pragma unroll
  for (int i = 0; i < 4; ++i)
    #pragma unroll
    for (int j = 0; j < 6; ++j) acc[i][j] = 0.f;

  for (int k0 = 0; k0 < D_MODEL; k0 += G1_BK) {
    // stage x tile transposed: 32 rows x 64 k  (512 float4, 4 per thread)
    #pragma unroll
    for (int s = 0; s < 4; ++s) {
      int f = s * 128 + tid;
      int r = f >> 4;
      int k4 = f & 15;
      const float4 v = *reinterpret_cast<const float4*>(
          &x[(size_t)(m0 + r) * D_MODEL + k0 + k4 * 4]);
      sX[k4 * 4 + 0][r] = v.x; sX[k4 * 4 + 1][r] = v.y;
      sX[k4 * 4 + 2][r] = v.z; sX[k4 * 4 + 3][r] = v.w;
    }
    // stage W tile transposed: 96 e x 64 k  (1536 float4, 12 per thread)
    #pragma unroll
    for (int s = 0; s < 12; ++s) {
      int f = s * 128 + tid;
      int e = f >> 4;
      int k4 = f & 15;
      const float4 v = *reinterpret_cast<const float4*>(
          &W[(size_t)e * D_MODEL + k0 + k4 * 4]);
      sW[k4 * 4 + 0][e] = v.x; sW[k4 * 4 + 1][e] = v.y;
      sW[k4 * 4 + 2][e] = v.z; sW[k4 * 4 + 3][e] = v.w;
    }
    __syncthreads();
    #pragma unroll 8
    for (int k = 0; k < G1_BK; ++k) {
      const float4 a = *reinterpret_cast<const float4*>(&sX[k][tx * 4]);
      const float av[4] = {a.x, a.y, a.z, a.w};
      #pragma unroll
      for (int j = 0; j < 6; ++j) {
        const float bv = sW[k][ty * 6 + j];
        #pragma unroll
        for (int i = 0; i < 4; ++i) acc[i][j] = fmaf(av[i], bv, acc[i][j]);
      }
    }
    __syncthreads();
  }
  #pragma unroll
  for (int i = 0; i < 4; ++i) {
    const int m = m0 + tx * 4 + i;
    #pragma unroll
    for (int j = 0; j < 6; ++j)
      dtBC[(size_t)m * E_DIM + ty * 6 + j] = acc[i][j];
  }
}

// ---------------------------------------------------------------------------
// Kernel 2: dt[m][d] = softplus(sum_r dtBC[m][r] * W2[d][r] + b2[d])
// K=64. One thread per column d, 16 rows per thread (register-cached W chunk).
// ---------------------------------------------------------------------------
#define G2_ROWS 16

__global__ __launch_bounds__(256)
void k_dt(const float* __restrict__ dtBC, const float* __restrict__ W2,
          const float* __restrict__ b2, float* __restrict__ dt) {
  const int d = blockIdx.x * 256 + threadIdx.x;
  const int m0 = blockIdx.y * G2_ROWS;
  const float bias = b2[d];
  float acc[G2_ROWS];
  #pragma unroll
  for (int i = 0; i < G2_ROWS; ++i) acc[i] = bias;

  #pragma unroll
  for (int k4 = 0; k4 < DT_RANK / 4; ++k4) {
    const float4 w = *reinterpret_cast<const float4*>(
        &W2[(size_t)d * DT_RANK + k4 * 4]);
    #pragma unroll
    for (int i = 0; i < G2_ROWS; ++i) {
      const float4 a = *reinterpret_cast<const float4*>(
          &dtBC[(size_t)(m0 + i) * E_DIM + k4 * 4]);
      acc[i] = fmaf(a.x, w.x, acc[i]);
      acc[i] = fmaf(a.y, w.y, acc[i]);
      acc[i] = fmaf(a.z, w.z, acc[i]);
      acc[i] = fmaf(a.w, w.w, acc[i]);
    }
  }
  #pragma unroll
  for (int i = 0; i < G2_ROWS; ++i) {
    const float a = acc[i];
    const float sp = (a > 15.f) ? a : __logf(1.f + __expf(a));
    dt[(size_t)(m0 + i) * D_MODEL + d] = sp;
  }
}

// ---------------------------------------------------------------------------
// Kernel 3 (phase A): per-chunk transfer (P = prod dA, U = folded input sum)
// thread = (b, chunk, d); 16-wide state in registers.
// Layout of P/U/hst: [b][c][n][d]  (d-coalesced)
// ---------------------------------------------------------------------------
__global__ __launch_bounds__(256)
void k_scanA(const float* __restrict__ dt, const float* __restrict__ x,
             const float* __restrict__ dtBC, const float* __restrict__ A_log,
             float* __restrict__ P, float* __restrict__ U) {
  const int d = blockIdx.x * 256 + threadIdx.x;
  const int c = blockIdx.y;
  const int b = blockIdx.z;
  const int t0 = c * CHUNK;

  __shared__ float sB[CHUNK][D_STATE];   // 4 KB
  for (int idx = threadIdx.x; idx < CHUNK * D_STATE; idx += 256) {
    const int t = idx >> 4, n = idx & 15;
    sB[t][n] = dtBC[(size_t)(b * SEQLEN + t0 + t) * E_DIM + DT_RANK + n];
  }
  __syncthreads();

  float Ar[D_STATE];
  #pragma unroll
  for (int q = 0; q < 4; ++q) {
    const float4 v = *reinterpret_cast<const float4*>(
        &A_log[(size_t)d * D_STATE + q * 4]);
    Ar[q * 4 + 0] = -__expf(v.x); Ar[q * 4 + 1] = -__expf(v.y);
    Ar[q * 4 + 2] = -__expf(v.z); Ar[q * 4 + 3] = -__expf(v.w);
  }

  float Pr[D_STATE], Ur[D_STATE];
  #pragma unroll
  for (int n = 0; n < D_STATE; ++n) { Pr[n] = 1.f; Ur[n] = 0.f; }

  const float* dtp = dt + (size_t)(b * SEQLEN + t0) * D_MODEL + d;
  const float* xp  = x  + (size_t)(b * SEQLEN + t0) * D_MODEL + d;

  for (int t = 0; t < CHUNK; ++t) {
    const float dtv = dtp[(size_t)t * D_MODEL];
    const float xv  = xp[(size_t)t * D_MODEL];
    const float z = dtv * xv;
    #pragma unroll
    for (int n = 0; n < D_STATE; ++n) {
      const float e = __expf(dtv * Ar[n]);
      Ur[n] = fmaf(e, Ur[n], z * sB[t][n]);
      Pr[n] *= e;
    }
  }
  const size_t base = (size_t)(b * NCHUNK + c) * (D_STATE * D_MODEL) + d;
  #pragma unroll
  for (int n = 0; n < D_STATE; ++n) {
    P[base + (size_t)n * D_MODEL] = Pr[n];
    U[base + (size_t)n * D_MODEL] = Ur[n];
  }
}

// ---------------------------------------------------------------------------
// Kernel 4 (phase B): sequential inter-chunk scan; writes chunk-start states.
// thread = (b, n, d): 32768 threads, 64 chunk steps.
// ---------------------------------------------------------------------------
__global__ __launch_bounds__(256)
void k_scanB(const float* __restrict__ P, const float* __restrict__ U,
             float* __restrict__ hst) {
  const int idx = blockIdx.x * 256 + threadIdx.x;   // b*16384 + n*1024 + d
  const int b = idx >> 14;
  const int nd = idx & 16383;
  float h = 0.f;
  for (int c = 0; c < NCHUNK; ++c) {
    const size_t off = (size_t)(b * NCHUNK + c) * (D_STATE * D_MODEL) + nd;
    hst[off] = h;
    h = fmaf(P[off], h, U[off]);
  }
}

// ---------------------------------------------------------------------------
// Kernel 5 (phase C): replay within chunk from hst, produce y.
// ---------------------------------------------------------------------------
__global__ __launch_bounds__(256)
void k_scanC(const float* __restrict__ dt, const float* __restrict__ x,
             const float* __restrict__ dtBC, const float* __restrict__ A_log,
             const float* __restrict__ Dp, const float* __restrict__ hst,
             float* __restrict__ y) {
  const int d = blockIdx.x * 256 + threadIdx.x;
  const int c = blockIdx.y;
  const int b = blockIdx.z;
  const int t0 = c * CHUNK;

  __shared__ float sBC[CHUNK][2 * D_STATE];   // 8 KB: [t][0..15]=B, [t][16..31]=C
  for (int idx = threadIdx.x; idx < CHUNK * 2 * D_STATE; idx += 256) {
    const int t = idx >> 5, j = idx & 31;
    sBC[t][j] = dtBC[(size_t)(b * SEQLEN + t0 + t) * E_DIM + DT_RANK + j];
  }
  __syncthreads();

  float Ar[D_STATE];
  #pragma unroll
  for (int q = 0; q < 4; ++q) {
    const float4 v = *reinterpret_cast<const float4*>(
        &A_log[(size_t)d * D_STATE + q * 4]);
    Ar[q * 4 + 0] = -__expf(v.x); Ar[q * 4 + 1] = -__expf(v.y);
    Ar[q * 4 + 2] = -__expf(v.z); Ar[q * 4 + 3] = -__expf(v.w);
  }
  const float Dv = Dp[d];

  float h[D_STATE];
  const size_t hbase = (size_t)(b * NCHUNK + c) * (D_STATE * D_MODEL) + d;
  #pragma unroll
  for (int n = 0; n < D_STATE; ++n) h[n] = hst[hbase + (size_t)n * D_MODEL];

  const float* dtp = dt + (size_t)(b * SEQLEN + t0) * D_MODEL + d;
  const float* xp  = x  + (size_t)(b * SEQLEN + t0) * D_MODEL + d;
  float* yp        = y  + (size_t)(b * SEQLEN + t0) * D_MODEL + d;

  for (int t = 0; t < CHUNK; ++t) {
    const float dtv = dtp[(size_t)t * D_MODEL];
    const float xv  = xp[(size_t)t * D_MODEL];
    const float z = dtv * xv;
    float acc = 0.f;
    #pragma unroll
    for (int n = 0; n < D_STATE; ++n) {
      const float e = __expf(dtv * Ar[n]);
      h[n] = fmaf(e, h[n], z * sBC[t][n]);
      acc = fmaf(h[n], sBC[t][D_STATE + n], acc);
    }
    yp[(size_t)t * D_MODEL] = fmaf(xv, Dv, acc);
  }
}

extern "C" void kernel_launch(void* const* d_in, const int* in_sizes, int n_in,
                              void* d_out, int out_size, void* d_ws, size_t ws_size,
                              hipStream_t stream) {
  const float* x     = (const float*)d_in[0];
  const float* A_log = (const float*)d_in[1];
  const float* Dp    = (const float*)d_in[2];
  const float* W2    = (const float*)d_in[3];   // dt_proj_w (1024,64)
  const float* b2    = (const float*)d_in[4];   // dt_proj_b (1024,)
  const float* Wx    = (const float*)d_in[5];   // x_to_dtBC_w (96,1024)
  float* out = (float*)d_out;

  float* ws    = (float*)d_ws;
  float* dtBC  = ws;                 //   786,432 floats
  float* dtbuf = ws + 786432;        // 8,388,608 floats
  float* P     = ws + 9175040;       // 2,097,152 floats
  float* U     = ws + 11272192;      // 2,097,152 floats
  float* hst   = ws + 13369344;      // 2,097,152 floats  (total ~62 MB)

  hipLaunchKernelGGL(k_gemm1, dim3(NROWS / G1_BM), dim3(128), 0, stream,
                     x, Wx, dtBC);
  hipLaunchKernelGGL(k_dt, dim3(D_MODEL / 256, NROWS / G2_ROWS), dim3(256), 0,
                     stream, dtBC, W2, b2, dtbuf);
  hipLaunchKernelGGL(k_scanA, dim3(D_MODEL / 256, NCHUNK, BATCH), dim3(256), 0,
                     stream, dtbuf, x, dtBC, A_log, P, U);
  hipLaunchKernelGGL(k_scanB, dim3((BATCH * D_STATE * D_MODEL) / 256), dim3(256),
                     0, stream, P, U, hst);
  hipLaunchKernelGGL(k_scanC, dim3(D_MODEL / 256, NCHUNK, BATCH), dim3(256), 0,
                     stream, dtbuf, x, dtBC, A_log, Dp, hst, out);
}

// Round 3
// 244.941 us; speedup vs baseline: 1.0923x; 1.0923x over previous
//
#include <hip/hip_runtime.h>

#define D_MODEL 1024
#define D_STATE 16
#define DT_RANK 64
#define BATCH 2
#define SEQLEN 4096
#define NROWS (BATCH * SEQLEN)           // 8192
#define E_DIM (DT_RANK + 2 * D_STATE)    // 96

// ---------------------------------------------------------------------------
// Kernel 1: partial GEMM  dtBC_part[ks][m][e] = sum_{k in seg ks} x[m][k]*W[e][k]
// M=8192, N=96, K=1024 split into KSPLIT segments. 128 thr, BM=32, BK=64.
// sX stored column-rotation-swizzled: element (k,r) at sX[k][(r + 4*(k>>2)) & 31]
//  -> staging writes 2-way (free), ds_read_b128 aligned + conflict-free.
// ---------------------------------------------------------------------------
#define G1_BM 32
#define G1_BK 64
#define KSPLIT 4
#define KSEG (D_MODEL / KSPLIT)          // 256

__global__ __launch_bounds__(128)
void k_gemm1(const float* __restrict__ x, const float* __restrict__ W,
             float* __restrict__ parts) {
  __shared__ float sX[G1_BK][32];          // swizzled, 8 KB
  __shared__ float sW[G1_BK][E_DIM + 1];   // [k][e], stride 97, ~24.8 KB
  const int tid = threadIdx.x;
  const int m0 = blockIdx.x * G1_BM;
  const int kseg0 = blockIdx.y * KSEG;
  const int tx = tid & 7;          // rows tx*4 .. tx*4+3
  const int ty = tid >> 3;         // cols ty*6 .. ty*6+5

  float acc[4][6];
  #pragma unroll
  for (int i = 0; i < 4; ++i)
    #pragma unroll
    for (int j = 0; j < 6; ++j) acc[i][j] = 0.f;

  for (int kk = 0; kk < KSEG; kk += G1_BK) {
    const int k0 = kseg0 + kk;
    // stage x tile: 32 rows x 64 k (512 float4 loads, 4/thread), swizzled store
    #pragma unroll
    for (int s = 0; s < 4; ++s) {
      const int f = s * 128 + tid;
      const int r = f >> 4;
      const int k4 = f & 15;
      const float4 v = *reinterpret_cast<const float4*>(
          &x[(size_t)(m0 + r) * D_MODEL + k0 + k4 * 4]);
      const int col = (r + 4 * k4) & 31;   // (k>>2)==k4 for k=4*k4+c
      sX[k4 * 4 + 0][col] = v.x; sX[k4 * 4 + 1][col] = v.y;
      sX[k4 * 4 + 2][col] = v.z; sX[k4 * 4 + 3][col] = v.w;
    }
    // stage W tile: 96 e x 64 k (1536 float4 loads, 12/thread)
    #pragma unroll
    for (int s = 0; s < 12; ++s) {
      const int f = s * 128 + tid;
      const int e = f >> 4;
      const int k4 = f & 15;
      const float4 v = *reinterpret_cast<const float4*>(
          &W[(size_t)e * D_MODEL + k0 + k4 * 4]);
      sW[k4 * 4 + 0][e] = v.x; sW[k4 * 4 + 1][e] = v.y;
      sW[k4 * 4 + 2][e] = v.z; sW[k4 * 4 + 3][e] = v.w;
    }
    __syncthreads();
    #pragma unroll 8
    for (int k = 0; k < G1_BK; ++k) {
      const int cb = (4 * tx + 4 * (k >> 2)) & 31;   // base col of this thread's 4 rows
      const float4 a = *reinterpret_cast<const float4*>(&sX[k][cb]);
      const float av[4] = {a.x, a.y, a.z, a.w};
      #pragma unroll
      for (int j = 0; j < 6; ++j) {
        const float bv = sW[k][ty * 6 + j];
        #pragma unroll
        for (int i = 0; i < 4; ++i) acc[i][j] = fmaf(av[i], bv, acc[i][j]);
      }
    }
    __syncthreads();
  }
  float* outp = parts + (size_t)blockIdx.y * NROWS * E_DIM;
  #pragma unroll
  for (int i = 0; i < 4; ++i) {
    const int m = m0 + tx * 4 + i;
    #pragma unroll
    for (int j = 0; j < 6; ++j)
      outp[(size_t)m * E_DIM + ty * 6 + j] = acc[i][j];
  }
}

// Sum the KSPLIT partials -> dtBC. 786432 floats = 196608 float4.
__global__ __launch_bounds__(256)
void k_reduce(const float* __restrict__ parts, float* __restrict__ dtBC) {
  const int i = blockIdx.x * 256 + threadIdx.x;
  const float4* p = reinterpret_cast<const float4*>(parts);
  float4 a = p[i];
  #pragma unroll
  for (int s = 1; s < KSPLIT; ++s) {
    const float4 b = p[(size_t)s * (NROWS * E_DIM / 4) + i];
    a.x += b.x; a.y += b.y; a.z += b.z; a.w += b.w;
  }
  reinterpret_cast<float4*>(dtBC)[i] = a;
}

// Transpose W2 (1024x64) -> W2T (64x1024) so k_dt reads coalesce.
__global__ __launch_bounds__(256)
void k_trW2(const float* __restrict__ W2, float* __restrict__ W2T) {
  const int idx = blockIdx.x * 256 + threadIdx.x;   // 65536 total
  const int r = idx >> 10;
  const int d = idx & 1023;
  W2T[idx] = W2[(size_t)d * DT_RANK + r];
}

// ---------------------------------------------------------------------------
// Kernel 2: dt[m][d] = softplus(sum_r dtBC[m][r] * W2T[r][d] + b2[d])
// dtBC reads are block-uniform (scalarized); W2T reads coalesced.
// ---------------------------------------------------------------------------
#define G2_ROWS 16

__global__ __launch_bounds__(256)
void k_dt(const float* __restrict__ dtBC, const float* __restrict__ W2T,
          const float* __restrict__ b2, float* __restrict__ dt) {
  const int d = blockIdx.x * 256 + threadIdx.x;
  const int m0 = blockIdx.y * G2_ROWS;
  const float bias = b2[d];
  float acc[G2_ROWS];
  #pragma unroll
  for (int i = 0; i < G2_ROWS; ++i) acc[i] = bias;

  for (int r = 0; r < DT_RANK; ++r) {
    const float w = W2T[(size_t)r * D_MODEL + d];
    #pragma unroll
    for (int i = 0; i < G2_ROWS; ++i)
      acc[i] = fmaf(dtBC[(size_t)(m0 + i) * E_DIM + r], w, acc[i]);
  }
  #pragma unroll
  for (int i = 0; i < G2_ROWS; ++i) {
    const float a = acc[i];
    const float sp = (a > 15.f) ? a : __logf(1.f + __expf(a));
    dt[(size_t)(m0 + i) * D_MODEL + d] = sp;
  }
}

// ---------------------------------------------------------------------------
// Phase A: per-chunk transfer (P = prod dA, U = folded input sum).
// Layout of P/U/hst: [b][c][n][d] (d-coalesced). Manual 1-deep load pipeline.
// ---------------------------------------------------------------------------
template <int CH>
__global__ __launch_bounds__(256)
void k_scanA(const float* __restrict__ dt, const float* __restrict__ x,
             const float* __restrict__ dtBC, const float* __restrict__ A_log,
             float* __restrict__ P, float* __restrict__ U) {
  const int d = blockIdx.x * 256 + threadIdx.x;
  const int c = blockIdx.y;
  const int b = blockIdx.z;
  const int t0 = c * CH;
  const int nch = SEQLEN / CH;

  __shared__ float sB[CH][D_STATE];
  for (int idx = threadIdx.x; idx < CH * D_STATE; idx += 256) {
    const int t = idx >> 4, n = idx & 15;
    sB[t][n] = dtBC[(size_t)(b * SEQLEN + t0 + t) * E_DIM + DT_RANK + n];
  }
  __syncthreads();

  float Ar[D_STATE];
  #pragma unroll
  for (int q = 0; q < 4; ++q) {
    const float4 v = *reinterpret_cast<const float4*>(
        &A_log[(size_t)d * D_STATE + q * 4]);
    Ar[q * 4 + 0] = -__expf(v.x); Ar[q * 4 + 1] = -__expf(v.y);
    Ar[q * 4 + 2] = -__expf(v.z); Ar[q * 4 + 3] = -__expf(v.w);
  }

  float Pr[D_STATE], Ur[D_STATE];
  #pragma unroll
  for (int n = 0; n < D_STATE; ++n) { Pr[n] = 1.f; Ur[n] = 0.f; }

  const float* dtp = dt + (size_t)(b * SEQLEN + t0) * D_MODEL + d;
  const float* xp  = x  + (size_t)(b * SEQLEN + t0) * D_MODEL + d;

  float dtv = dtp[0];
  float xv  = xp[0];
  for (int t = 0; t < CH - 1; ++t) {
    const float dtn = dtp[(size_t)(t + 1) * D_MODEL];
    const float xn  = xp[(size_t)(t + 1) * D_MODEL];
    const float z = dtv * xv;
    #pragma unroll
    for (int n = 0; n < D_STATE; ++n) {
      const float e = __expf(dtv * Ar[n]);
      Ur[n] = fmaf(e, Ur[n], z * sB[t][n]);
      Pr[n] *= e;
    }
    dtv = dtn; xv = xn;
  }
  {
    const float z = dtv * xv;
    #pragma unroll
    for (int n = 0; n < D_STATE; ++n) {
      const float e = __expf(dtv * Ar[n]);
      Ur[n] = fmaf(e, Ur[n], z * sB[CH - 1][n]);
      Pr[n] *= e;
    }
  }
  const size_t base = (size_t)(b * nch + c) * (D_STATE * D_MODEL) + d;
  #pragma unroll
  for (int n = 0; n < D_STATE; ++n) {
    P[base + (size_t)n * D_MODEL] = Pr[n];
    U[base + (size_t)n * D_MODEL] = Ur[n];
  }
}

// ---------------------------------------------------------------------------
// Phase B: sequential inter-chunk scan; writes chunk-start states.
// ---------------------------------------------------------------------------
__global__ __launch_bounds__(256)
void k_scanB(const float* __restrict__ P, const float* __restrict__ U,
             float* __restrict__ hst, const int nchunk) {
  const int idx = blockIdx.x * 256 + threadIdx.x;   // b*16384 + n*1024 + d
  const int b = idx >> 14;
  const int nd = idx & 16383;
  float h = 0.f;
  for (int c = 0; c < nchunk; ++c) {
    const size_t off = (size_t)(b * nchunk + c) * (D_STATE * D_MODEL) + nd;
    hst[off] = h;
    h = fmaf(P[off], h, U[off]);
  }
}

// ---------------------------------------------------------------------------
// Phase C: replay within chunk from hst, produce y.
// ---------------------------------------------------------------------------
template <int CH>
__global__ __launch_bounds__(256)
void k_scanC(const float* __restrict__ dt, const float* __restrict__ x,
             const float* __restrict__ dtBC, const float* __restrict__ A_log,
             const float* __restrict__ Dp, const float* __restrict__ hst,
             float* __restrict__ y) {
  const int d = blockIdx.x * 256 + threadIdx.x;
  const int c = blockIdx.y;
  const int b = blockIdx.z;
  const int t0 = c * CH;
  const int nch = SEQLEN / CH;

  __shared__ float sBC[CH][2 * D_STATE];   // [t][0..15]=B, [t][16..31]=C
  for (int idx = threadIdx.x; idx < CH * 2 * D_STATE; idx += 256) {
    const int t = idx >> 5, j = idx & 31;
    sBC[t][j] = dtBC[(size_t)(b * SEQLEN + t0 + t) * E_DIM + DT_RANK + j];
  }
  __syncthreads();

  float Ar[D_STATE];
  #pragma unroll
  for (int q = 0; q < 4; ++q) {
    const float4 v = *reinterpret_cast<const float4*>(
        &A_log[(size_t)d * D_STATE + q * 4]);
    Ar[q * 4 + 0] = -__expf(v.x); Ar[q * 4 + 1] = -__expf(v.y);
    Ar[q * 4 + 2] = -__expf(v.z); Ar[q * 4 + 3] = -__expf(v.w);
  }
  const float Dv = Dp[d];

  float h[D_STATE];
  const size_t hbase = (size_t)(b * nch + c) * (D_STATE * D_MODEL) + d;
  #pragma unroll
  for (int n = 0; n < D_STATE; ++n) h[n] = hst[hbase + (size_t)n * D_MODEL];

  const float* dtp = dt + (size_t)(b * SEQLEN + t0) * D_MODEL + d;
  const float* xp  = x  + (size_t)(b * SEQLEN + t0) * D_MODEL + d;
  float* yp        = y  + (size_t)(b * SEQLEN + t0) * D_MODEL + d;

  float dtv = dtp[0];
  float xv  = xp[0];
  for (int t = 0; t < CH; ++t) {
    float dtn = 0.f, xn = 0.f;
    if (t + 1 < CH) {
      dtn = dtp[(size_t)(t + 1) * D_MODEL];
      xn  = xp[(size_t)(t + 1) * D_MODEL];
    }
    const float z = dtv * xv;
    float acc = 0.f;
    #pragma unroll
    for (int n = 0; n < D_STATE; ++n) {
      const float e = __expf(dtv * Ar[n]);
      h[n] = fmaf(e, h[n], z * sBC[t][n]);
      acc = fmaf(h[n], sBC[t][D_STATE + n], acc);
    }
    yp[(size_t)t * D_MODEL] = fmaf(xv, Dv, acc);
    dtv = dtn; xv = xn;
  }
}

extern "C" void kernel_launch(void* const* d_in, const int* in_sizes, int n_in,
                              void* d_out, int out_size, void* d_ws, size_t ws_size,
                              hipStream_t stream) {
  const float* x     = (const float*)d_in[0];
  const float* A_log = (const float*)d_in[1];
  const float* Dp    = (const float*)d_in[2];
  const float* W2    = (const float*)d_in[3];   // dt_proj_w (1024,64)
  const float* b2    = (const float*)d_in[4];   // dt_proj_b (1024,)
  const float* Wx    = (const float*)d_in[5];   // x_to_dtBC_w (96,1024)
  float* out = (float*)d_out;

  float* ws = (float*)d_ws;

  // CHUNK=32 layout needs ~99.6 MB of ws; fall back to CHUNK=64 (~62 MB) if short.
  const size_t need32 = (size_t)(786432 + 8388608 + 3145728 + 3 * 4194304) * 4;
  const bool big = ws_size >= need32;

  float* dtBC  = ws;                        // 786,432
  float* dtbuf = ws + 786432;               // 8,388,608

  if (big) {
    const int CH = 32, NCH = SEQLEN / 32;
    float* parts = ws + 9175040;            // 3,145,728
    float* P     = ws + 12320768;           // 4,194,304
    float* U     = ws + 16515072;           // 4,194,304
    float* hst   = ws + 20709376;           // 4,194,304
    float* W2T   = hst;                     // alias: dead before scanB writes hst

    hipLaunchKernelGGL(k_gemm1, dim3(NROWS / G1_BM, KSPLIT), dim3(128), 0,
                       stream, x, Wx, parts);
    hipLaunchKernelGGL(k_reduce, dim3(NROWS * E_DIM / 4 / 256), dim3(256), 0,
                       stream, parts, dtBC);
    hipLaunchKernelGGL(k_trW2, dim3(D_MODEL * DT_RANK / 256), dim3(256), 0,
                       stream, W2, W2T);
    hipLaunchKernelGGL(k_dt, dim3(D_MODEL / 256, NROWS / G2_ROWS), dim3(256), 0,
                       stream, dtBC, W2T, b2, dtbuf);
    hipLaunchKernelGGL(k_scanA<32>, dim3(D_MODEL / 256, NCH, BATCH), dim3(256),
                       0, stream, dtbuf, x, dtBC, A_log, P, U);
    hipLaunchKernelGGL(k_scanB, dim3((BATCH * D_STATE * D_MODEL) / 256),
                       dim3(256), 0, stream, P, U, hst, NCH);
    hipLaunchKernelGGL(k_scanC<32>, dim3(D_MODEL / 256, NCH, BATCH), dim3(256),
                       0, stream, dtbuf, x, dtBC, A_log, Dp, hst, out);
  } else {
    const int CH = 64, NCH = SEQLEN / 64;
    float* P     = ws + 9175040;            // 2,097,152
    float* U     = ws + 11272192;           // 2,097,152
    float* hst   = ws + 13369344;           // 2,097,152
    float* parts = P;                       // alias: dead before scanA writes P/U
    float* W2T   = hst;                     // alias: dead before scanB writes hst

    hipLaunchKernelGGL(k_gemm1, dim3(NROWS / G1_BM, KSPLIT), dim3(128), 0,
                       stream, x, Wx, parts);
    hipLaunchKernelGGL(k_reduce, dim3(NROWS * E_DIM / 4 / 256), dim3(256), 0,
                       stream, parts, dtBC);
    hipLaunchKernelGGL(k_trW2, dim3(D_MODEL * DT_RANK / 256), dim3(256), 0,
                       stream, W2, W2T);
    hipLaunchKernelGGL(k_dt, dim3(D_MODEL / 256, NROWS / G2_ROWS), dim3(256), 0,
                       stream, dtBC, W2T, b2, dtbuf);
    hipLaunchKernelGGL(k_scanA<64>, dim3(D_MODEL / 256, NCH, BATCH), dim3(256),
                       0, stream, dtbuf, x, dtBC, A_log, P, U);
    hipLaunchKernelGGL(k_scanB, dim3((BATCH * D_STATE * D_MODEL) / 256),
                       dim3(256), 0, stream, P, U, hst, NCH);
    hipLaunchKernelGGL(k_scanC<64>, dim3(D_MODEL / 256, NCH, BATCH), dim3(256),
                       0, stream, dtbuf, x, dtBC, A_log, Dp, hst, out);
  }
}

// Round 4
// 235.315 us; speedup vs baseline: 1.1369x; 1.0409x over previous
//
#include <hip/hip_runtime.h>

#define D_MODEL 1024
#define D_STATE 16
#define DT_RANK 64
#define BATCH 2
#define SEQLEN 4096
#define NROWS (BATCH * SEQLEN)           // 8192
#define E_DIM (DT_RANK + 2 * D_STATE)    // 96
#define CH 32
#define NCH (SEQLEN / CH)                // 128

// ---------------------------------------------------------------------------
// k_trans: WT[k][e] = Wx[e][k]  (1024x96)  and  W2T[r][d] = W2[d][r] (64x1024)
// ---------------------------------------------------------------------------
__global__ __launch_bounds__(256)
void k_trans(const float* __restrict__ Wx, const float* __restrict__ W2,
             float* __restrict__ WT, float* __restrict__ W2T) {
  const int bid = blockIdx.x;
  if (bid < 384) {                       // 384*256 = 98304 = 1024*96
    const int idx = bid * 256 + threadIdx.x;
    const int k = idx / E_DIM;
    const int e = idx - k * E_DIM;
    WT[idx] = Wx[(size_t)e * D_MODEL + k];
  } else {                               // 256*256 = 65536 = 64*1024
    const int idx = (bid - 384) * 256 + threadIdx.x;
    const int r = idx >> 10;
    const int d = idx & 1023;
    W2T[idx] = W2[(size_t)d * DT_RANK + r];
  }
}

// ---------------------------------------------------------------------------
// Kernel 1: partial GEMM, M=8192 N=96 K=1024, KSPLIT=8 (K=128/block).
// lane = row (BM=64); wave w owns cols w*48..w*48+47 (uniform -> s_load of WT).
// Only x is LDS-staged ([k][65] padded: 2-way conflicts = free).
// ---------------------------------------------------------------------------
#define G1_BM 64
#define KSPLIT 8
#define KSEG (D_MODEL / KSPLIT)          // 128

__global__ __launch_bounds__(128)
void k_gemm1(const float* __restrict__ x, const float* __restrict__ WT,
             float* __restrict__ parts) {
  __shared__ float sX[64 * 65];          // 16.6 KB
  const int tid = threadIdx.x;
  const int lane = tid & 63;
  const int e0 = __builtin_amdgcn_readfirstlane((tid >> 6) * 48);
  const int m0 = blockIdx.x * G1_BM;
  const int ks0 = blockIdx.y * KSEG;

  float acc[48];
  #pragma unroll
  for (int j = 0; j < 48; ++j) acc[j] = 0.f;

  for (int kk = 0; kk < KSEG; kk += 64) {
    __syncthreads();
    // stage 64 rows x 64 k of x, transposed into [k][r] (stride 65)
    #pragma unroll
    for (int s = 0; s < 8; ++s) {
      const int f = s * 128 + tid;
      const int r = f >> 4;
      const int k4 = f & 15;
      const float4 v = *reinterpret_cast<const float4*>(
          &x[(size_t)(m0 + r) * D_MODEL + ks0 + kk + k4 * 4]);
      sX[(k4 * 4 + 0) * 65 + r] = v.x;
      sX[(k4 * 4 + 1) * 65 + r] = v.y;
      sX[(k4 * 4 + 2) * 65 + r] = v.z;
      sX[(k4 * 4 + 3) * 65 + r] = v.w;
    }
    __syncthreads();
    #pragma unroll 4
    for (int k = 0; k < 64; ++k) {
      const float xv = sX[k * 65 + lane];
      const float* wrow = WT + (size_t)(ks0 + kk + k) * E_DIM + e0;
      #pragma unroll
      for (int q = 0; q < 12; ++q) {
        const float4 w = *reinterpret_cast<const float4*>(wrow + 4 * q);
        acc[4 * q + 0] = fmaf(xv, w.x, acc[4 * q + 0]);
        acc[4 * q + 1] = fmaf(xv, w.y, acc[4 * q + 1]);
        acc[4 * q + 2] = fmaf(xv, w.z, acc[4 * q + 2]);
        acc[4 * q + 3] = fmaf(xv, w.w, acc[4 * q + 3]);
      }
    }
  }
  float* op = parts + (size_t)blockIdx.y * (NROWS * E_DIM)
            + (size_t)(m0 + lane) * E_DIM + e0;
  #pragma unroll
  for (int q = 0; q < 12; ++q)
    *reinterpret_cast<float4*>(op + 4 * q) =
        make_float4(acc[4 * q + 0], acc[4 * q + 1], acc[4 * q + 2], acc[4 * q + 3]);
}

// Sum the KSPLIT partials -> dtBC. 786432 floats = 196608 float4.
__global__ __launch_bounds__(256)
void k_reduce(const float* __restrict__ parts, float* __restrict__ dtBC) {
  const int i = blockIdx.x * 256 + threadIdx.x;
  const float4* p = reinterpret_cast<const float4*>(parts);
  float4 a = p[i];
  #pragma unroll
  for (int s = 1; s < KSPLIT; ++s) {
    const float4 b = p[(size_t)s * (NROWS * E_DIM / 4) + i];
    a.x += b.x; a.y += b.y; a.z += b.z; a.w += b.w;
  }
  reinterpret_cast<float4*>(dtBC)[i] = a;
}

// ---------------------------------------------------------------------------
// Kernel 2: dt[m][d] = softplus(sum_r dtBC[m][r] * W2T[r][d] + b2[d])
// ---------------------------------------------------------------------------
#define G2_ROWS 16

__global__ __launch_bounds__(256)
void k_dt(const float* __restrict__ dtBC, const float* __restrict__ W2T,
          const float* __restrict__ b2, float* __restrict__ dt) {
  const int d = blockIdx.x * 256 + threadIdx.x;
  const int m0 = blockIdx.y * G2_ROWS;
  const float bias = b2[d];
  float acc[G2_ROWS];
  #pragma unroll
  for (int i = 0; i < G2_ROWS; ++i) acc[i] = bias;

  for (int r = 0; r < DT_RANK; ++r) {
    const float w = W2T[(size_t)r * D_MODEL + d];
    #pragma unroll
    for (int i = 0; i < G2_ROWS; ++i)
      acc[i] = fmaf(dtBC[(size_t)(m0 + i) * E_DIM + r], w, acc[i]);
  }
  #pragma unroll
  for (int i = 0; i < G2_ROWS; ++i) {
    const float a = acc[i];
    const float sp = (a > 15.f) ? a : __logf(1.f + __expf(a));
    dt[(size_t)(m0 + i) * D_MODEL + d] = sp;
  }
}

// ---------------------------------------------------------------------------
// Phase A: per-chunk transfer (P = prod dA, U = folded input sum).
// Layout of P/U/hst: [b][c][n][d] (d-coalesced).
// ---------------------------------------------------------------------------
__global__ __launch_bounds__(256)
void k_scanA(const float* __restrict__ dt, const float* __restrict__ x,
             const float* __restrict__ dtBC, const float* __restrict__ A_log,
             float* __restrict__ P, float* __restrict__ U) {
  const int d = blockIdx.x * 256 + threadIdx.x;
  const int c = blockIdx.y;
  const int b = blockIdx.z;
  const int t0 = c * CH;

  __shared__ float sB[CH][D_STATE];
  for (int idx = threadIdx.x; idx < CH * D_STATE; idx += 256) {
    const int t = idx >> 4, n = idx & 15;
    sB[t][n] = dtBC[(size_t)(b * SEQLEN + t0 + t) * E_DIM + DT_RANK + n];
  }
  __syncthreads();

  float Ar[D_STATE];
  #pragma unroll
  for (int q = 0; q < 4; ++q) {
    const float4 v = *reinterpret_cast<const float4*>(
        &A_log[(size_t)d * D_STATE + q * 4]);
    Ar[q * 4 + 0] = -__expf(v.x); Ar[q * 4 + 1] = -__expf(v.y);
    Ar[q * 4 + 2] = -__expf(v.z); Ar[q * 4 + 3] = -__expf(v.w);
  }

  float Pr[D_STATE], Ur[D_STATE];
  #pragma unroll
  for (int n = 0; n < D_STATE; ++n) { Pr[n] = 1.f; Ur[n] = 0.f; }

  const float* dtp = dt + (size_t)(b * SEQLEN + t0) * D_MODEL + d;
  const float* xp  = x  + (size_t)(b * SEQLEN + t0) * D_MODEL + d;

  float dtv = dtp[0];
  float xv  = xp[0];
  for (int t = 0; t < CH; ++t) {
    float dtn = 0.f, xn = 0.f;
    if (t + 1 < CH) {
      dtn = dtp[(size_t)(t + 1) * D_MODEL];
      xn  = xp[(size_t)(t + 1) * D_MODEL];
    }
    const float z = dtv * xv;
    #pragma unroll
    for (int n = 0; n < D_STATE; ++n) {
      const float e = __expf(dtv * Ar[n]);
      Ur[n] = fmaf(e, Ur[n], z * sB[t][n]);
      Pr[n] *= e;
    }
    dtv = dtn; xv = xn;
  }
  const size_t base = (size_t)(b * NCH + c) * (D_STATE * D_MODEL) + d;
  #pragma unroll
  for (int n = 0; n < D_STATE; ++n) {
    P[base + (size_t)n * D_MODEL] = Pr[n];
    U[base + (size_t)n * D_MODEL] = Ur[n];
  }
}

// ---------------------------------------------------------------------------
// Phase B: sequential inter-chunk scan; writes chunk-start states.
// ---------------------------------------------------------------------------
__global__ __launch_bounds__(256)
void k_scanB(const float* __restrict__ P, const float* __restrict__ U,
             float* __restrict__ hst) {
  const int idx = blockIdx.x * 256 + threadIdx.x;   // b*16384 + n*1024 + d
  const int b = idx >> 14;
  const int nd = idx & 16383;
  float h = 0.f;
  for (int c = 0; c < NCH; ++c) {
    const size_t off = (size_t)(b * NCH + c) * (D_STATE * D_MODEL) + nd;
    hst[off] = h;
    h = fmaf(P[off], h, U[off]);
  }
}

// ---------------------------------------------------------------------------
// Phase C: replay within chunk from hst, produce y.
// ---------------------------------------------------------------------------
__global__ __launch_bounds__(256)
void k_scanC(const float* __restrict__ dt, const float* __restrict__ x,
             const float* __restrict__ dtBC, const float* __restrict__ A_log,
             const float* __restrict__ Dp, const float* __restrict__ hst,
             float* __restrict__ y) {
  const int d = blockIdx.x * 256 + threadIdx.x;
  const int c = blockIdx.y;
  const int b = blockIdx.z;
  const int t0 = c * CH;

  __shared__ float sBC[CH][2 * D_STATE];   // [t][0..15]=B, [t][16..31]=C
  for (int idx = threadIdx.x; idx < CH * 2 * D_STATE; idx += 256) {
    const int t = idx >> 5, j = idx & 31;
    sBC[t][j] = dtBC[(size_t)(b * SEQLEN + t0 + t) * E_DIM + DT_RANK + j];
  }
  __syncthreads();

  float Ar[D_STATE];
  #pragma unroll
  for (int q = 0; q < 4; ++q) {
    const float4 v = *reinterpret_cast<const float4*>(
        &A_log[(size_t)d * D_STATE + q * 4]);
    Ar[q * 4 + 0] = -__expf(v.x); Ar[q * 4 + 1] = -__expf(v.y);
    Ar[q * 4 + 2] = -__expf(v.z); Ar[q * 4 + 3] = -__expf(v.w);
  }
  const float Dv = Dp[d];

  float h[D_STATE];
  const size_t hbase = (size_t)(b * NCH + c) * (D_STATE * D_MODEL) + d;
  #pragma unroll
  for (int n = 0; n < D_STATE; ++n) h[n] = hst[hbase + (size_t)n * D_MODEL];

  const float* dtp = dt + (size_t)(b * SEQLEN + t0) * D_MODEL + d;
  const float* xp  = x  + (size_t)(b * SEQLEN + t0) * D_MODEL + d;
  float* yp        = y  + (size_t)(b * SEQLEN + t0) * D_MODEL + d;

  float dtv = dtp[0];
  float xv  = xp[0];
  for (int t = 0; t < CH; ++t) {
    float dtn = 0.f, xn = 0.f;
    if (t + 1 < CH) {
      dtn = dtp[(size_t)(t + 1) * D_MODEL];
      xn  = xp[(size_t)(t + 1) * D_MODEL];
    }
    const float z = dtv * xv;
    float acc = 0.f;
    #pragma unroll
    for (int n = 0; n < D_STATE; ++n) {
      const float e = __expf(dtv * Ar[n]);
      h[n] = fmaf(e, h[n], z * sBC[t][n]);
      acc = fmaf(h[n], sBC[t][D_STATE + n], acc);
    }
    yp[(size_t)t * D_MODEL] = fmaf(xv, Dv, acc);
    dtv = dtn; xv = xn;
  }
}

extern "C" void kernel_launch(void* const* d_in, const int* in_sizes, int n_in,
                              void* d_out, int out_size, void* d_ws, size_t ws_size,
                              hipStream_t stream) {
  const float* x     = (const float*)d_in[0];
  const float* A_log = (const float*)d_in[1];
  const float* Dp    = (const float*)d_in[2];
  const float* W2    = (const float*)d_in[3];   // dt_proj_w (1024,64)
  const float* b2    = (const float*)d_in[4];   // dt_proj_b (1024,)
  const float* Wx    = (const float*)d_in[5];   // x_to_dtBC_w (96,1024)
  float* out = (float*)d_out;

  float* ws = (float*)d_ws;
  // layout (floats):
  float* dtBC  = ws;                    //   786,432
  float* dtbuf = ws +   786432;         // 8,388,608
  float* P     = ws +  9175040;         // 4,194,304
  float* U     = ws + 13369344;         // 4,194,304
  float* hst   = ws + 17563648;         // 4,194,304  (end 21,757,952 = 87 MB)
  float* parts = P;                     // alias: 6,291,456 <= P+U, dead after k_reduce
  float* WT    = hst;                   // alias: 98,304, dead before k_scanB
  float* W2T   = hst + 98304;           // alias: 65,536, dead before k_scanB

  hipLaunchKernelGGL(k_trans, dim3(640), dim3(256), 0, stream, Wx, W2, WT, W2T);
  hipLaunchKernelGGL(k_gemm1, dim3(NROWS / G1_BM, KSPLIT), dim3(128), 0,
                     stream, x, WT, parts);
  hipLaunchKernelGGL(k_reduce, dim3(NROWS * E_DIM / 4 / 256), dim3(256), 0,
                     stream, parts, dtBC);
  hipLaunchKernelGGL(k_dt, dim3(D_MODEL / 256, NROWS / G2_ROWS), dim3(256), 0,
                     stream, dtBC, W2T, b2, dtbuf);
  hipLaunchKernelGGL(k_scanA, dim3(D_MODEL / 256, NCH, BATCH), dim3(256),
                     0, stream, dtbuf, x, dtBC, A_log, P, U);
  hipLaunchKernelGGL(k_scanB, dim3((BATCH * D_STATE * D_MODEL) / 256),
                     dim3(256), 0, stream, P, U, hst);
  hipLaunchKernelGGL(k_scanC, dim3(D_MODEL / 256, NCH, BATCH), dim3(256),
                     0, stream, dtbuf, x, dtBC, A_log, Dp, hst, out);
}

// Round 5
// 217.480 us; speedup vs baseline: 1.2302x; 1.0820x over previous
//
#include <hip/hip_runtime.h>

#define D_MODEL 1024
#define D_STATE 16
#define DT_RANK 64
#define BATCH 2
#define SEQLEN 4096
#define NROWS (BATCH * SEQLEN)           // 8192
#define E_DIM 96
#define CH 32
#define NCH (SEQLEN / CH)                // 128

typedef short bf16x8 __attribute__((ext_vector_type(8)));
typedef float f32x4 __attribute__((ext_vector_type(4)));

// ---------------------------------------------------------------------------
// k_prep: Wx (96x1024 fp32) -> Wx_bf (bf16, same layout, RNE)
//         W2 (1024x64)      -> W2T (64x1024 fp32)
// ---------------------------------------------------------------------------
__global__ __launch_bounds__(256)
void k_prep(const float* __restrict__ Wx, const float* __restrict__ W2,
            unsigned short* __restrict__ Wxbf, float* __restrict__ W2T) {
  const int bid = blockIdx.x;
  if (bid < 384) {                       // 384*256 = 98304 = 96*1024
    const int idx = bid * 256 + threadIdx.x;
    const float f = Wx[idx];
    unsigned int u = __float_as_uint(f);
    u = (u + 0x7fffu + ((u >> 16) & 1u)) >> 16;   // RNE, matches v_cvt_pk_bf16
    Wxbf[idx] = (unsigned short)u;
  } else {                               // 256*256 = 65536 = 64*1024
    const int idx = (bid - 384) * 256 + threadIdx.x;
    const int r = idx >> 10;
    const int d = idx & 1023;
    W2T[idx] = W2[(size_t)d * DT_RANK + r];
  }
}

// ---------------------------------------------------------------------------
// Kernel 1: dtBC[m][e] = sum_k x[m][k] * Wx[e][k]  via bf16 MFMA 16x16x32.
// One wave per 16-row M-tile; 6 N-tiles of 16; K = 32 steps of 32.
// A-frag: lane l holds x[m0+(l&15)][k0+(l>>4)*8 + j], j=0..7 (cvt_pk to bf16)
// B-frag: lane l holds Wx[e0+(l&15)][k0+(l>>4)*8 + j]  (16B load of Wx_bf)
// D:      row=(l>>4)*4+i, col=l&15  [m89-verified]
// ---------------------------------------------------------------------------
__global__ __launch_bounds__(64)
void k_gemm1(const float* __restrict__ x, const unsigned short* __restrict__ Wxbf,
             float* __restrict__ dtBC) {
  const int lane = threadIdx.x;
  const int m0 = blockIdx.x * 16;
  const int r = lane & 15;
  const int kq = lane >> 4;              // 0..3

  f32x4 acc[6];
  #pragma unroll
  for (int j = 0; j < 6; ++j) acc[j] = (f32x4){0.f, 0.f, 0.f, 0.f};

  const float* xrow = x + (size_t)(m0 + r) * D_MODEL + kq * 8;
  const unsigned short* wbase = Wxbf + (size_t)r * D_MODEL + kq * 8;

  #pragma unroll 2
  for (int k0 = 0; k0 < D_MODEL; k0 += 32) {
    const float4 a0 = *reinterpret_cast<const float4*>(xrow + k0);
    const float4 a1 = *reinterpret_cast<const float4*>(xrow + k0 + 4);
    union { unsigned int u[4]; bf16x8 v; } ua;
    asm("v_cvt_pk_bf16_f32 %0, %1, %2" : "=v"(ua.u[0]) : "v"(a0.x), "v"(a0.y));
    asm("v_cvt_pk_bf16_f32 %0, %1, %2" : "=v"(ua.u[1]) : "v"(a0.z), "v"(a0.w));
    asm("v_cvt_pk_bf16_f32 %0, %1, %2" : "=v"(ua.u[2]) : "v"(a1.x), "v"(a1.y));
    asm("v_cvt_pk_bf16_f32 %0, %1, %2" : "=v"(ua.u[3]) : "v"(a1.z), "v"(a1.w));
    const bf16x8 af = ua.v;
    #pragma unroll
    for (int j = 0; j < 6; ++j) {
      const bf16x8 bf = *reinterpret_cast<const bf16x8*>(
          wbase + (size_t)j * 16 * D_MODEL + k0);
      acc[j] = __builtin_amdgcn_mfma_f32_16x16x32_bf16(af, bf, acc[j], 0, 0, 0);
    }
  }
  #pragma unroll
  for (int j = 0; j < 6; ++j)
    #pragma unroll
    for (int i = 0; i < 4; ++i)
      dtBC[(size_t)(m0 + kq * 4 + i) * E_DIM + j * 16 + r] = acc[j][i];
}

// ---------------------------------------------------------------------------
// Kernel 2: dt[m][d] = softplus(sum_r dtBC[m][r] * W2T[r][d] + b2[d])
// ---------------------------------------------------------------------------
#define G2_ROWS 16

__global__ __launch_bounds__(256)
void k_dt(const float* __restrict__ dtBC, const float* __restrict__ W2T,
          const float* __restrict__ b2, float* __restrict__ dt) {
  const int d = blockIdx.x * 256 + threadIdx.x;
  const int m0 = blockIdx.y * G2_ROWS;
  const float bias = b2[d];
  float acc[G2_ROWS];
  #pragma unroll
  for (int i = 0; i < G2_ROWS; ++i) acc[i] = bias;

  for (int r = 0; r < DT_RANK; ++r) {
    const float w = W2T[(size_t)r * D_MODEL + d];
    #pragma unroll
    for (int i = 0; i < G2_ROWS; ++i)
      acc[i] = fmaf(dtBC[(size_t)(m0 + i) * E_DIM + r], w, acc[i]);
  }
  #pragma unroll
  for (int i = 0; i < G2_ROWS; ++i) {
    const float a = acc[i];
    const float sp = (a > 15.f) ? a : __logf(1.f + __expf(a));
    dt[(size_t)(m0 + i) * D_MODEL + d] = sp;
  }
}

// ---------------------------------------------------------------------------
// Phase A: per-chunk transfer (P = prod dA, U = folded input sum).
// Layout of P/U/hst: [b][c][n][d] (d-coalesced).
// ---------------------------------------------------------------------------
__global__ __launch_bounds__(256)
void k_scanA(const float* __restrict__ dt, const float* __restrict__ x,
             const float* __restrict__ dtBC, const float* __restrict__ A_log,
             float* __restrict__ P, float* __restrict__ U) {
  const int d = blockIdx.x * 256 + threadIdx.x;
  const int c = blockIdx.y;
  const int b = blockIdx.z;
  const int t0 = c * CH;

  __shared__ float sB[CH][D_STATE];
  for (int idx = threadIdx.x; idx < CH * D_STATE; idx += 256) {
    const int t = idx >> 4, n = idx & 15;
    sB[t][n] = dtBC[(size_t)(b * SEQLEN + t0 + t) * E_DIM + DT_RANK + n];
  }
  __syncthreads();

  float Ar[D_STATE];
  #pragma unroll
  for (int q = 0; q < 4; ++q) {
    const float4 v = *reinterpret_cast<const float4*>(
        &A_log[(size_t)d * D_STATE + q * 4]);
    Ar[q * 4 + 0] = -__expf(v.x); Ar[q * 4 + 1] = -__expf(v.y);
    Ar[q * 4 + 2] = -__expf(v.z); Ar[q * 4 + 3] = -__expf(v.w);
  }

  float Pr[D_STATE], Ur[D_STATE];
  #pragma unroll
  for (int n = 0; n < D_STATE; ++n) { Pr[n] = 1.f; Ur[n] = 0.f; }

  const float* dtp = dt + (size_t)(b * SEQLEN + t0) * D_MODEL + d;
  const float* xp  = x  + (size_t)(b * SEQLEN + t0) * D_MODEL + d;

  float dtv = dtp[0];
  float xv  = xp[0];
  for (int t = 0; t < CH; ++t) {
    float dtn = 0.f, xn = 0.f;
    if (t + 1 < CH) {
      dtn = dtp[(size_t)(t + 1) * D_MODEL];
      xn  = xp[(size_t)(t + 1) * D_MODEL];
    }
    const float z = dtv * xv;
    #pragma unroll
    for (int n = 0; n < D_STATE; ++n) {
      const float e = __expf(dtv * Ar[n]);
      Ur[n] = fmaf(e, Ur[n], z * sB[t][n]);
      Pr[n] *= e;
    }
    dtv = dtn; xv = xn;
  }
  const size_t base = (size_t)(b * NCH + c) * (D_STATE * D_MODEL) + d;
  #pragma unroll
  for (int n = 0; n < D_STATE; ++n) {
    P[base + (size_t)n * D_MODEL] = Pr[n];
    U[base + (size_t)n * D_MODEL] = Ur[n];
  }
}

// ---------------------------------------------------------------------------
// Phase B: sequential inter-chunk scan; writes chunk-start states.
// ---------------------------------------------------------------------------
__global__ __launch_bounds__(256)
void k_scanB(const float* __restrict__ P, const float* __restrict__ U,
             float* __restrict__ hst) {
  const int idx = blockIdx.x * 256 + threadIdx.x;   // b*16384 + n*1024 + d
  const int b = idx >> 14;
  const int nd = idx & 16383;
  float h = 0.f;
  for (int c = 0; c < NCH; ++c) {
    const size_t off = (size_t)(b * NCH + c) * (D_STATE * D_MODEL) + nd;
    hst[off] = h;
    h = fmaf(P[off], h, U[off]);
  }
}

// ---------------------------------------------------------------------------
// Phase C: replay within chunk from hst, produce y.
// ---------------------------------------------------------------------------
__global__ __launch_bounds__(256)
void k_scanC(const float* __restrict__ dt, const float* __restrict__ x,
             const float* __restrict__ dtBC, const float* __restrict__ A_log,
             const float* __restrict__ Dp, const float* __restrict__ hst,
             float* __restrict__ y) {
  const int d = blockIdx.x * 256 + threadIdx.x;
  const int c = blockIdx.y;
  const int b = blockIdx.z;
  const int t0 = c * CH;

  __shared__ float sBC[CH][2 * D_STATE];   // [t][0..15]=B, [t][16..31]=C
  for (int idx = threadIdx.x; idx < CH * 2 * D_STATE; idx += 256) {
    const int t = idx >> 5, j = idx & 31;
    sBC[t][j] = dtBC[(size_t)(b * SEQLEN + t0 + t) * E_DIM + DT_RANK + j];
  }
  __syncthreads();

  float Ar[D_STATE];
  #pragma unroll
  for (int q = 0; q < 4; ++q) {
    const float4 v = *reinterpret_cast<const float4*>(
        &A_log[(size_t)d * D_STATE + q * 4]);
    Ar[q * 4 + 0] = -__expf(v.x); Ar[q * 4 + 1] = -__expf(v.y);
    Ar[q * 4 + 2] = -__expf(v.z); Ar[q * 4 + 3] = -__expf(v.w);
  }
  const float Dv = Dp[d];

  float h[D_STATE];
  const size_t hbase = (size_t)(b * NCH + c) * (D_STATE * D_MODEL) + d;
  #pragma unroll
  for (int n = 0; n < D_STATE; ++n) h[n] = hst[hbase + (size_t)n * D_MODEL];

  const float* dtp = dt + (size_t)(b * SEQLEN + t0) * D_MODEL + d;
  const float* xp  = x  + (size_t)(b * SEQLEN + t0) * D_MODEL + d;
  float* yp        = y  + (size_t)(b * SEQLEN + t0) * D_MODEL + d;

  float dtv = dtp[0];
  float xv  = xp[0];
  for (int t = 0; t < CH; ++t) {
    float dtn = 0.f, xn = 0.f;
    if (t + 1 < CH) {
      dtn = dtp[(size_t)(t + 1) * D_MODEL];
      xn  = xp[(size_t)(t + 1) * D_MODEL];
    }
    const float z = dtv * xv;
    float acc = 0.f;
    #pragma unroll
    for (int n = 0; n < D_STATE; ++n) {
      const float e = __expf(dtv * Ar[n]);
      h[n] = fmaf(e, h[n], z * sBC[t][n]);
      acc = fmaf(h[n], sBC[t][D_STATE + n], acc);
    }
    yp[(size_t)t * D_MODEL] = fmaf(xv, Dv, acc);
    dtv = dtn; xv = xn;
  }
}

extern "C" void kernel_launch(void* const* d_in, const int* in_sizes, int n_in,
                              void* d_out, int out_size, void* d_ws, size_t ws_size,
                              hipStream_t stream) {
  const float* x     = (const float*)d_in[0];
  const float* A_log = (const float*)d_in[1];
  const float* Dp    = (const float*)d_in[2];
  const float* W2    = (const float*)d_in[3];   // dt_proj_w (1024,64)
  const float* b2    = (const float*)d_in[4];   // dt_proj_b (1024,)
  const float* Wx    = (const float*)d_in[5];   // x_to_dtBC_w (96,1024)
  float* out = (float*)d_out;

  float* ws = (float*)d_ws;
  // layout (floats):
  float* dtBC  = ws;                    //   786,432
  float* dtbuf = ws +   786432;         // 8,388,608
  float* P     = ws +  9175040;         // 4,194,304
  float* U     = ws + 13369344;         // 4,194,304
  float* hst   = ws + 17563648;         // 4,194,304  (end 21,757,952 = 87 MB)
  // aliases into hst (dead before k_scanB writes hst):
  unsigned short* Wxbf = (unsigned short*)hst;        // 98,304 bf16 = 49,152 fl
  float* W2T           = hst + 49152;                 // 65,536 fl

  hipLaunchKernelGGL(k_prep, dim3(640), dim3(256), 0, stream, Wx, W2, Wxbf, W2T);
  hipLaunchKernelGGL(k_gemm1, dim3(NROWS / 16), dim3(64), 0, stream,
                     x, Wxbf, dtBC);
  hipLaunchKernelGGL(k_dt, dim3(D_MODEL / 256, NROWS / G2_ROWS), dim3(256), 0,
                     stream, dtBC, W2T, b2, dtbuf);
  hipLaunchKernelGGL(k_scanA, dim3(D_MODEL / 256, NCH, BATCH), dim3(256),
                     0, stream, dtbuf, x, dtBC, A_log, P, U);
  hipLaunchKernelGGL(k_scanB, dim3((BATCH * D_STATE * D_MODEL) / 256),
                     dim3(256), 0, stream, P, U, hst);
  hipLaunchKernelGGL(k_scanC, dim3(D_MODEL / 256, NCH, BATCH), dim3(256),
                     0, stream, dtbuf, x, dtBC, A_log, Dp, hst, out);
}